// Round 17
// baseline (357.802 us; speedup 1.0000x reference)
//
#include <hip/hip_runtime.h>
#include <cstddef>
#include <cstdint>

#define E_TOTAL 3200000
#define N_NODES 100000
#define N_RELS 50
#define N_BASES 16
#define HD 16
#define OD 8
#define NTHR 256

#define NBKT 196       // coarse buckets: dst >> 9 (512 dsts each)
#define P1B 1024       // p1 blocks
#define P1C 3125       // edges per p1 block
#define WFB 76         // wrf tail blocks
#define E0B 1563       // e0f tail blocks
#define FP8_SCALE 256.0f
#define FP8_INV (1.0f / 256.0f)

typedef unsigned int u32;
typedef __attribute__((ext_vector_type(8))) short s16x8;
typedef __attribute__((ext_vector_type(4))) float f32x4;
typedef __attribute__((ext_vector_type(16))) float f32x16;

__device__ __forceinline__ u32 cvtpk(float x0, float x1) {  // v_cvt_pk_bf16_f32 (RNE)
    u32 r;
    asm("v_cvt_pk_bf16_f32 %0, %1, %2" : "=v"(r) : "v"(x0), "v"(x1));
    return r;
}
__device__ __forceinline__ ushort bf16r(float x) {
    u32 a = __float_as_uint(x);
    return (ushort)((a + 0x7fffu + ((a >> 16) & 1u)) >> 16);
}
__device__ __forceinline__ s16x8 as_s16x8(uint4 u) {
    union { uint4 u; s16x8 s; } x; x.u = u; return x.s;
}

// ---- fp8: HW pack/unpack (self-consistent encoding on gfx950) ----
#if __has_builtin(__builtin_amdgcn_cvt_pk_fp8_f32)
__device__ __forceinline__ u32 pk8x4(float a, float b, float c, float d) {
    int v = __builtin_amdgcn_cvt_pk_fp8_f32(a, b, 0, false);   // low word
    v = __builtin_amdgcn_cvt_pk_fp8_f32(c, d, v, true);        // high word
    return (u32)v;
}
#else
__device__ __forceinline__ u32 pk8(float v) {
    u32 x = __float_as_uint(v);
    u32 s = (x >> 24) & 0x80u;
    u32 ax = x & 0x7fffffffu;
    int e = (int)(ax >> 23) - 127;
    if (e < -9) return s;
    if (e < -6) {
        u32 m = (u32)rintf(__uint_as_float(ax) * 512.0f);
        if (m == 0) return s;
        if (m >= 8) return s | 0x08u;
        return s | m;
    }
    u32 m = ax & 0x7fffffu;
    u32 keep = m >> 20, rest = m & 0xFFFFFu;
    keep += (rest > 0x80000u) || (rest == 0x80000u && (keep & 1u));
    u32 ee = (u32)(e + 7);
    if (keep == 8u) { keep = 0u; ee += 1u; }
    if (ee > 15u || (ee == 15u && keep == 7u)) return s | 0x7eu;
    return s | (ee << 3) | keep;
}
__device__ __forceinline__ u32 pk8x4(float a, float b, float c, float d) {
    return pk8(a) | (pk8(b) << 8) | (pk8(c) << 16) | (pk8(d) << 24);
}
#endif
#if __has_builtin(__builtin_amdgcn_cvt_f32_fp8)
template <int SEL>
__device__ __forceinline__ float up8(u32 q) { return __builtin_amdgcn_cvt_f32_fp8(q, SEL); }
#else
template <int SEL>
__device__ __forceinline__ float up8(u32 q) {
    u32 b = (q >> (SEL * 8)) & 0xffu;
    u32 em = b & 0x7fu;
    float v = (em >= 8u) ? __uint_as_float((((em >> 3) + 120u) << 23) | ((em & 7u) << 20))
                         : (float)em * (1.0f / 512.0f);
    return (b & 0x80u) ? -v : v;
}
#endif

// ====== p1 (fused with wrf-frag build AND e0f table build — all independent) ======
// Sort segment: direct scatter into block-private tmp slice (L2-resident, full-line coverage);
// no LDS staging -> 2.6 KB LDS, high occupancy.
__global__ __launch_bounds__(NTHR) void k_p1(const int* __restrict__ esrc, const int* __restrict__ edst,
                                             const int* __restrict__ erel, const float* __restrict__ enorm,
                                             uint2* __restrict__ tmp, int* __restrict__ cntK,
                                             int* __restrict__ runstartK,
                                             const float* __restrict__ W1, const float* __restrict__ C1,
                                             const float* __restrict__ W2, const float* __restrict__ C2,
                                             ushort* __restrict__ f1, ushort* __restrict__ f2,
                                             const float* __restrict__ W0, const float* __restrict__ C0,
                                             u32* __restrict__ emb) {
    __shared__ int lcnt[NBKT];
    __shared__ int sc[NTHR];
    __shared__ int lcur[NBKT];
    int tid = threadIdx.x;
    if (blockIdx.x >= P1B + WFB) {  // ---- e0f tail blocks ----
        const f32x16 z16 = {0.f, 0.f, 0.f, 0.f, 0.f, 0.f, 0.f, 0.f,
                            0.f, 0.f, 0.f, 0.f, 0.f, 0.f, 0.f, 0.f};
        int lane = tid & 63;
        int col = lane & 31, hi = lane >> 5;
        s16x8 bf0, bf1;
        {
            float v[8];
            #pragma unroll
            for (int e = 0; e < 8; ++e) v[e] = C0[col * 16 + hi * 8 + e] * FP8_SCALE;
            bf0 = as_s16x8(make_uint4(cvtpk(v[0], v[1]), cvtpk(v[2], v[3]),
                                      cvtpk(v[4], v[5]), cvtpk(v[6], v[7])));
            int r1 = col + 32;
            #pragma unroll
            for (int e = 0; e < 8; ++e) v[e] = (r1 < N_RELS) ? C0[r1 * 16 + hi * 8 + e] * FP8_SCALE : 0.f;
            bf1 = as_s16x8(make_uint4(cvtpk(v[0], v[1]), cvtpk(v[2], v[3]),
                                      cvtpk(v[4], v[5]), cvtpk(v[6], v[7])));
        }
        int w = ((blockIdx.x - P1B - WFB) * NTHR + tid) >> 6;
        int nw = (E0B * NTHR) >> 6;
        bool g1ok = (col + 32) < N_RELS;
        for (int t = w; t < 50000; t += nw) {
            size_t gs = (size_t)t * 32 + col;
            float a[8];
            #pragma unroll
            for (int e = 0; e < 8; ++e)
                a[e] = W0[(size_t)(hi * 8 + e) * (N_NODES * HD) + gs];
            s16x8 af = as_s16x8(make_uint4(cvtpk(a[0], a[1]), cvtpk(a[2], a[3]),
                                           cvtpk(a[4], a[5]), cvtpk(a[6], a[7])));
            f32x16 d0 = __builtin_amdgcn_mfma_f32_32x32x16_bf16(af, bf0, z16, 0, 0, 0);
            f32x16 d1 = __builtin_amdgcn_mfma_f32_32x32x16_bf16(af, bf1, z16, 0, 0, 0);
            #pragma unroll
            for (int j = 0; j < 4; ++j) {
                size_t base = ((size_t)(t * 2 + (j >> 1)) * 50) * 4 + (size_t)((j & 1) * 2 + hi);
                emb[base + (size_t)col * 4] = pk8x4(d0[4 * j], d0[4 * j + 1], d0[4 * j + 2], d0[4 * j + 3]);
                if (g1ok)
                    emb[base + (size_t)(col + 32) * 4] =
                        pk8x4(d1[4 * j], d1[4 * j + 1], d1[4 * j + 2], d1[4 * j + 3]);
            }
        }
        return;
    }
    if (blockIdx.x >= P1B) {  // ---- wrf tail blocks ----
        int idx = (blockIdx.x - P1B) * NTHR + tid;
        if (idx < 25 * 512) {  // wf1
            int p = idx >> 9, rem = idx & 511, lane = rem >> 3, e = rem & 7;
            int m = lane & 31, kk = ((lane >> 5) << 3) + e;
            int r = 2 * p + (m >> 4), o = m & 15;
            float acc = 0.f;
            #pragma unroll
            for (int b = 0; b < N_BASES; ++b)
                acc = fmaf(C1[r * N_BASES + b], W1[b * 256 + kk * 16 + o], acc);
            f1[idx] = bf16r(acc * FP8_SCALE);
        } else if (idx < 25 * 512 + 13 * 512) {  // wf2
            int j = idx - 25 * 512;
            int g = j >> 9, rem = j & 511, lane = rem >> 3, e = rem & 7;
            int m = lane & 31, kk = ((lane >> 5) << 3) + e;
            int rl = 4 * g + (m >> 3), o = m & 7;
            float acc = 0.f;
            if (rl < N_RELS) {
                #pragma unroll
                for (int b = 0; b < N_BASES; ++b)
                    acc = fmaf(C2[rl * N_BASES + b], W2[b * 128 + kk * 8 + o], acc);
            }
            f2[j] = bf16r(acc * FP8_SCALE);
        }
        return;
    }
    // ---- sort segment: direct-scatter (no LDS staging) ----
    for (int i = tid; i < NBKT; i += NTHR) lcnt[i] = 0;
    __syncthreads();
    int e0 = blockIdx.x * P1C;
    u32 rx[13], rn[13];
    int rb[13];
    #pragma unroll
    for (int j = 0; j < 13; ++j) {
        int i = tid + j * NTHR;
        rb[j] = -1;
        if (i < P1C) {
            int e = e0 + i;
            int d = edst[e];
            int b = d >> 9;
            rb[j] = b;
            rx[j] = (u32)esrc[e] | ((u32)erel[e] << 17) | ((u32)(d & 511) << 23);
            rn[j] = __float_as_uint(enorm[e]);
            atomicAdd(&lcnt[b], 1);
        }
    }
    __syncthreads();
    int own = (tid < NBKT) ? lcnt[tid] : 0;
    sc[tid] = own;
    __syncthreads();
    #pragma unroll
    for (int off = 1; off < NTHR; off <<= 1) {
        int t = (tid >= off) ? sc[tid - off] : 0;
        __syncthreads();
        sc[tid] += t;
        __syncthreads();
    }
    if (tid < NBKT) lcur[tid] = sc[tid] - own;
    __syncthreads();
    uint2* slice = tmp + (size_t)blockIdx.x * P1C;
    #pragma unroll
    for (int j = 0; j < 13; ++j) {
        if (rb[j] >= 0) {
            int pos = atomicAdd(&lcur[rb[j]], 1);
            slice[pos] = make_uint2(rx[j], rn[j]);  // private 25 KB window, L2-resident
        }
    }
    __syncthreads();
    for (int b = tid; b < NBKT; b += NTHR) {
        int excl = lcur[b] - lcnt[b];
        cntK[blockIdx.x * NBKT + b] = lcnt[b];
        runstartK[blockIdx.x * NBKT + b] = blockIdx.x * P1C + excl;
    }
}

// bucket totals
__global__ __launch_bounds__(NTHR) void k_tot(const int* __restrict__ cntK, int* __restrict__ total) {
    int b = blockIdx.x;
    __shared__ int s[NTHR];
    int tid = threadIdx.x;
    int acc = 0;
    for (int k = tid; k < P1B; k += NTHR) acc += cntK[k * NBKT + b];
    s[tid] = acc;
    __syncthreads();
    for (int off = NTHR / 2; off > 0; off >>= 1) {
        if (tid < off) s[tid] += s[tid + off];
        __syncthreads();
    }
    if (tid == 0) total[b] = s[0];
}

// p2: self-computed base + per-dst sort within bucket (L2-resident window)
__global__ __launch_bounds__(1024) void k_p2(const uint2* __restrict__ tmp, const int* __restrict__ cntK,
                                             const int* __restrict__ runstartK, const int* __restrict__ total,
                                             uint2* __restrict__ rec, int* __restrict__ row_ptr) {
    int b = blockIdx.x;
    int tid = threadIdx.x;
    __shared__ int dcnt[512], dscan[512];
    __shared__ int gbs;
    if (tid < 256) dcnt[tid] = (tid < b && tid < NBKT) ? total[tid] : 0;
    __syncthreads();
    for (int off = 128; off > 0; off >>= 1) {
        if (tid < off) dcnt[tid] += dcnt[tid + off];
        __syncthreads();
    }
    if (tid == 0) gbs = dcnt[0];
    __syncthreads();
    int gbase = gbs;
    if (tid < 512) dcnt[tid] = 0;
    __syncthreads();
    int mycnt = cntK[tid * NBKT + b];
    int myrs = runstartK[tid * NBKT + b];
    for (int i = 0; i < mycnt; ++i)
        atomicAdd(&dcnt[tmp[myrs + i].x >> 23], 1);
    __syncthreads();
    if (tid < 512) dscan[tid] = dcnt[tid];
    __syncthreads();
    for (int off = 1; off < 512; off <<= 1) {
        int v = (tid >= off && tid < 512) ? dscan[tid - off] : 0;
        __syncthreads();
        if (tid < 512) dscan[tid] += v;
        __syncthreads();
    }
    if (tid < 512) {
        int excl = gbase + dscan[tid] - dcnt[tid];
        int d = (b << 9) + tid;
        if (d < N_NODES) row_ptr[d] = excl;
        dscan[tid] = excl;
    }
    if (b == NBKT - 1 && tid == 0) row_ptr[N_NODES] = E_TOTAL;
    __syncthreads();
    for (int i = 0; i < mycnt; ++i) {
        uint2 t = tmp[myrs + i];
        int pos = atomicAdd(&dscan[t.x >> 23], 1);
        rec[pos] = make_uint2(t.x & 0x7FFFFFu, t.y);
    }
}

// gather 16-dim fp8 rows by (rel,src), parametric layout, relu-fused, bf16x16 row out.
// 16 edge-groups x 4 lanes; 2-edge unroll for memory-level parallelism.
__global__ __launch_bounds__(NTHR) void k_g16b(const uint2* __restrict__ rec, const int* __restrict__ row_ptr,
                                               const u32* __restrict__ tbl, u32* __restrict__ hb,
                                               int srcMul, int relMul) {
    int lane = threadIdx.x & 63;
    int g = lane >> 2, l = lane & 3;
    int wave = (blockIdx.x * NTHR + threadIdx.x) >> 6;
    int nw = (gridDim.x * NTHR) >> 6;
    for (int d = wave; d < N_NODES; d += nw) {
        int s0 = row_ptr[d], s1 = row_ptr[d + 1];
        float a0 = 0.f, a1 = 0.f, a2 = 0.f, a3 = 0.f;
        for (int j = s0 + g; j < s1; j += 32) {
            uint2 rc0 = rec[j];
            int j1 = j + 16;
            bool ok = j1 < s1;
            uint2 rc1 = ok ? rec[j1] : make_uint2(0u, 0u);
            int src0 = rc0.x & 0x1FFFF, rel0 = rc0.x >> 17;
            float nm0 = __uint_as_float(rc0.y) * FP8_INV;
            int src1 = rc1.x & 0x1FFFF, rel1 = rc1.x >> 17;
            float nm1 = ok ? __uint_as_float(rc1.y) * FP8_INV : 0.f;
            u32 q0 = tbl[(size_t)src0 * srcMul + (size_t)rel0 * relMul + l];
            u32 q1 = tbl[(size_t)src1 * srcMul + (size_t)rel1 * relMul + l];
            a0 = fmaf(nm0, up8<0>(q0), a0);
            a1 = fmaf(nm0, up8<1>(q0), a1);
            a2 = fmaf(nm0, up8<2>(q0), a2);
            a3 = fmaf(nm0, up8<3>(q0), a3);
            a0 = fmaf(nm1, up8<0>(q1), a0);
            a1 = fmaf(nm1, up8<1>(q1), a1);
            a2 = fmaf(nm1, up8<2>(q1), a2);
            a3 = fmaf(nm1, up8<3>(q1), a3);
        }
        a0 += __shfl_xor(a0, 4);  a1 += __shfl_xor(a1, 4);  a2 += __shfl_xor(a2, 4);  a3 += __shfl_xor(a3, 4);
        a0 += __shfl_xor(a0, 8);  a1 += __shfl_xor(a1, 8);  a2 += __shfl_xor(a2, 8);  a3 += __shfl_xor(a3, 8);
        a0 += __shfl_xor(a0, 16); a1 += __shfl_xor(a1, 16); a2 += __shfl_xor(a2, 16); a3 += __shfl_xor(a3, 16);
        a0 += __shfl_xor(a0, 32); a1 += __shfl_xor(a1, 32); a2 += __shfl_xor(a2, 32); a3 += __shfl_xor(a3, 32);
        if (lane < 4) {
            uint2 pk = make_uint2(cvtpk(fmaxf(a0, 0.f), fmaxf(a1, 0.f)),
                                  cvtpk(fmaxf(a2, 0.f), fmaxf(a3, 0.f)));
            *(uint2*)(hb + (size_t)d * 8 + l * 2) = pk;  // fused relu, bf16
        }
    }
}

// emb1 via 32x32x16 MFMA: M=32 = 2 rels x 16 o, N=32 nodes, K=16 (exact). [r][n] layout.
__global__ __launch_bounds__(NTHR) void k_e1f(const uint4* __restrict__ wfrag, const uint4* __restrict__ hb,
                                              u32* __restrict__ emb) {
    const f32x16 z16 = {0.f, 0.f, 0.f, 0.f, 0.f, 0.f, 0.f, 0.f,
                        0.f, 0.f, 0.f, 0.f, 0.f, 0.f, 0.f, 0.f};
    int lane = threadIdx.x & 63;
    int w = (blockIdx.x * NTHR + threadIdx.x) >> 6;
    int p = w / 250, c = w % 250;  // 25 pairs x 250 slots
    if (p >= 25) return;
    s16x8 af = as_s16x8(wfrag[p * 64 + lane]);
    int col = lane & 31, hi = lane >> 5;
    size_t r0b = (size_t)(2 * p) * 400000, r1b = (size_t)(2 * p + 1) * 400000;
    for (int t = c; t < 3125; t += 250) {
        uint4 hq = hb[(size_t)(t * 32 + col) * 2 + hi];  // 1 KB/wave: 32 node rows
        f32x16 d = __builtin_amdgcn_mfma_f32_32x32x16_bf16(af, as_s16x8(hq), z16, 0, 0, 0);
        u32 A0 = pk8x4(d[0], d[1], d[2], d[3]);
        u32 B0 = pk8x4(d[4], d[5], d[6], d[7]);
        u32 A1 = pk8x4(d[8], d[9], d[10], d[11]);
        u32 B1 = pk8x4(d[12], d[13], d[14], d[15]);
        u32 pA0 = (u32)__shfl_xor((int)A0, 32);
        u32 pB0 = (u32)__shfl_xor((int)B0, 32);
        u32 pA1 = (u32)__shfl_xor((int)A1, 32);
        u32 pB1 = (u32)__shfl_xor((int)B1, 32);
        u32 off = t * 128 + col * 4;
        if (hi == 0) {
            *(uint2*)(emb + r0b + off) = make_uint2(A0, pA0);
            *(uint2*)(emb + r1b + off) = make_uint2(A1, pA1);
        } else {
            *(uint2*)(emb + r0b + off + 2) = make_uint2(pB0, B0);
            *(uint2*)(emb + r1b + off + 2) = make_uint2(pB1, B1);
        }
    }
}

// emb2 via 32x32x16 MFMA: M=32 = 4 rels x 8 o. [r][n] layout, no shuffles.
__global__ __launch_bounds__(NTHR) void k_e2f(const uint4* __restrict__ wfrag, const uint4* __restrict__ hb,
                                              u32* __restrict__ emb) {
    const f32x16 z16 = {0.f, 0.f, 0.f, 0.f, 0.f, 0.f, 0.f, 0.f,
                        0.f, 0.f, 0.f, 0.f, 0.f, 0.f, 0.f, 0.f};
    int lane = threadIdx.x & 63;
    int w = (blockIdx.x * NTHR + threadIdx.x) >> 6;
    int g = w / 250, c = w % 250;  // 13 groups x 250 slots
    if (g >= 13) return;
    s16x8 af = as_s16x8(wfrag[g * 64 + lane]);
    int col = lane & 31, hi = lane >> 5;
    for (int t = c; t < 3125; t += 250) {
        uint4 hq = hb[(size_t)(t * 32 + col) * 2 + hi];
        f32x16 d = __builtin_amdgcn_mfma_f32_32x32x16_bf16(af, as_s16x8(hq), z16, 0, 0, 0);
        #pragma unroll
        for (int j = 0; j < 4; ++j) {
            int rl = 4 * g + j;
            if (rl >= N_RELS) break;  // wave-uniform
            u32 wj = pk8x4(d[4 * j], d[4 * j + 1], d[4 * j + 2], d[4 * j + 3]);
            emb[(size_t)rl * 200000 + t * 64 + col * 2 + hi] = wj;
        }
    }
}

// gather 8-dim fp8 rows + fused softmax. 32 edge-groups x 2 lanes.
__global__ __launch_bounds__(NTHR) void k_g8sm(const uint2* __restrict__ rec, const int* __restrict__ row_ptr,
                                               const u32* __restrict__ tbl, float* __restrict__ out) {
    int lane = threadIdx.x & 63;
    int g = lane >> 1, l = lane & 1;
    int wave = (blockIdx.x * NTHR + threadIdx.x) >> 6;
    int nw = (gridDim.x * NTHR) >> 6;
    for (int d = wave; d < N_NODES; d += nw) {
        int s0 = row_ptr[d], s1 = row_ptr[d + 1];
        float a0 = 0.f, a1 = 0.f, a2 = 0.f, a3 = 0.f;
        for (int j = s0 + g; j < s1; j += 32) {
            uint2 rc = rec[j];
            int src = rc.x & 0x1FFFF;
            int rel = rc.x >> 17;
            float nm = __uint_as_float(rc.y) * FP8_INV;
            u32 q = tbl[((size_t)rel * N_NODES + src) * 2 + l];
            a0 = fmaf(nm, up8<0>(q), a0);
            a1 = fmaf(nm, up8<1>(q), a1);
            a2 = fmaf(nm, up8<2>(q), a2);
            a3 = fmaf(nm, up8<3>(q), a3);
        }
        a0 += __shfl_xor(a0, 2);  a1 += __shfl_xor(a1, 2);  a2 += __shfl_xor(a2, 2);  a3 += __shfl_xor(a3, 2);
        a0 += __shfl_xor(a0, 4);  a1 += __shfl_xor(a1, 4);  a2 += __shfl_xor(a2, 4);  a3 += __shfl_xor(a3, 4);
        a0 += __shfl_xor(a0, 8);  a1 += __shfl_xor(a1, 8);  a2 += __shfl_xor(a2, 8);  a3 += __shfl_xor(a3, 8);
        a0 += __shfl_xor(a0, 16); a1 += __shfl_xor(a1, 16); a2 += __shfl_xor(a2, 16); a3 += __shfl_xor(a3, 16);
        a0 += __shfl_xor(a0, 32); a1 += __shfl_xor(a1, 32); a2 += __shfl_xor(a2, 32); a3 += __shfl_xor(a3, 32);
        float mx = fmaxf(fmaxf(a0, a1), fmaxf(a2, a3));
        mx = fmaxf(mx, __shfl_xor(mx, 1));
        float e0 = __expf(a0 - mx), e1 = __expf(a1 - mx), e2 = __expf(a2 - mx), e3 = __expf(a3 - mx);
        float sm = e0 + e1 + e2 + e3;
        sm += __shfl_xor(sm, 1);
        float inv = 1.0f / sm;
        if (lane < 2)
            *(float4*)(out + (size_t)d * OD + l * 4) = make_float4(e0 * inv, e1 * inv, e2 * inv, e3 * inv);
    }
}

// ======= TIER B fallback (atomics, 16.1 MB) =======
#define NBLK 2560

__device__ __forceinline__ void fma4(float* acc, float c, float4 w) {
    acc[0] = fmaf(c, w.x, acc[0]);
    acc[1] = fmaf(c, w.y, acc[1]);
    acc[2] = fmaf(c, w.z, acc[2]);
    acc[3] = fmaf(c, w.w, acc[3]);
}

__global__ __launch_bounds__(NTHR) void k_wr(const float* __restrict__ W1, const float* __restrict__ C1,
                                             const float* __restrict__ W2, const float* __restrict__ C2,
                                             float* __restrict__ Wr1, float* __restrict__ Wr2) {
    int idx = blockIdx.x * NTHR + threadIdx.x;
    const int n1 = N_RELS * 256;
    if (idx < n1) {
        int r = idx >> 8, io = idx & 255;
        float acc = 0.f;
        #pragma unroll
        for (int b = 0; b < N_BASES; ++b)
            acc = fmaf(C1[r * N_BASES + b], W1[b * 256 + io], acc);
        Wr1[idx] = acc;
    } else if (idx < n1 + N_RELS * 128) {
        int j = idx - n1;
        int r = j >> 7, io = j & 127;
        float acc = 0.f;
        #pragma unroll
        for (int b = 0; b < N_BASES; ++b)
            acc = fmaf(C2[r * N_BASES + b], W2[b * 128 + io], acc);
        Wr2[j] = acc;
    }
}

__global__ __launch_bounds__(NTHR) void k_l0_old(const int* __restrict__ esrc, const int* __restrict__ edst,
                                                 const int* __restrict__ erel, const float* __restrict__ enorm,
                                                 const float* __restrict__ W0, const float* __restrict__ C0,
                                                 float* __restrict__ h0) {
    for (int e = blockIdx.x * NTHR + threadIdx.x; e < E_TOTAL; e += NBLK * NTHR) {
        int s = esrc[e], d = edst[e], r = erel[e];
        float nm = enorm[e];
        const float4* cp = reinterpret_cast<const float4*>(C0 + r * N_BASES);
        float4 c0 = cp[0], c1 = cp[1], c2 = cp[2], c3 = cp[3];
        float coef[16] = {c0.x, c0.y, c0.z, c0.w, c1.x, c1.y, c1.z, c1.w,
                          c2.x, c2.y, c2.z, c2.w, c3.x, c3.y, c3.z, c3.w};
        float acc[16];
        #pragma unroll
        for (int h = 0; h < 16; ++h) acc[h] = 0.f;
        const float* wbase = W0 + (size_t)s * HD;
        #pragma unroll
        for (int b = 0; b < N_BASES; ++b) {
            const float4* wp = reinterpret_cast<const float4*>(wbase + (size_t)b * (N_NODES * HD));
            float cb = coef[b];
            fma4(acc + 0, cb, wp[0]);
            fma4(acc + 4, cb, wp[1]);
            fma4(acc + 8, cb, wp[2]);
            fma4(acc + 12, cb, wp[3]);
        }
        float* outp = h0 + (size_t)d * HD;
        #pragma unroll
        for (int h = 0; h < 16; ++h) atomicAdd(outp + h, nm * acc[h]);
    }
}

__global__ __launch_bounds__(NTHR) void k_l1_old(const int* __restrict__ esrc, const int* __restrict__ edst,
                                                 const int* __restrict__ erel, const float* __restrict__ enorm,
                                                 const float* __restrict__ h0, const float* __restrict__ Wr1,
                                                 float* __restrict__ h1) {
    __shared__ float w[N_RELS * 260];
    for (int i = threadIdx.x; i < N_RELS * 256; i += NTHR) {
        int r = i >> 8, rest = i & 255;
        w[r * 260 + rest] = Wr1[i];
    }
    __syncthreads();
    for (int e = blockIdx.x * NTHR + threadIdx.x; e < E_TOTAL; e += NBLK * NTHR) {
        int s = esrc[e], d = edst[e], r = erel[e];
        float nm = enorm[e];
        const float4* hp = reinterpret_cast<const float4*>(h0 + (size_t)s * HD);
        float4 hv0 = hp[0], hv1 = hp[1], hv2 = hp[2], hv3 = hp[3];
        float hs[16] = {fmaxf(hv0.x, 0.f), fmaxf(hv0.y, 0.f), fmaxf(hv0.z, 0.f), fmaxf(hv0.w, 0.f),
                        fmaxf(hv1.x, 0.f), fmaxf(hv1.y, 0.f), fmaxf(hv1.z, 0.f), fmaxf(hv1.w, 0.f),
                        fmaxf(hv2.x, 0.f), fmaxf(hv2.y, 0.f), fmaxf(hv2.z, 0.f), fmaxf(hv2.w, 0.f),
                        fmaxf(hv3.x, 0.f), fmaxf(hv3.y, 0.f), fmaxf(hv3.z, 0.f), fmaxf(hv3.w, 0.f)};
        float acc[16];
        #pragma unroll
        for (int h = 0; h < 16; ++h) acc[h] = 0.f;
        const float* wr = w + r * 260;
        #pragma unroll
        for (int i = 0; i < 16; ++i) {
            float hi = hs[i];
            const float4* wp = reinterpret_cast<const float4*>(wr + i * 16);
            fma4(acc + 0, hi, wp[0]);
            fma4(acc + 4, hi, wp[1]);
            fma4(acc + 8, hi, wp[2]);
            fma4(acc + 12, hi, wp[3]);
        }
        float* outp = h1 + (size_t)d * HD;
        #pragma unroll
        for (int h = 0; h < 16; ++h) atomicAdd(outp + h, nm * acc[h]);
    }
}

__global__ __launch_bounds__(NTHR) void k_l2_old(const int* __restrict__ esrc, const int* __restrict__ edst,
                                                 const int* __restrict__ erel, const float* __restrict__ enorm,
                                                 const float* __restrict__ h1, const float* __restrict__ Wr2,
                                                 float* __restrict__ h2) {
    __shared__ float w[N_RELS * 132];
    for (int i = threadIdx.x; i < N_RELS * 128; i += NTHR) {
        int r = i >> 7, rest = i & 127;
        w[r * 132 + rest] = Wr2[i];
    }
    __syncthreads();
    for (int e = blockIdx.x * NTHR + threadIdx.x; e < E_TOTAL; e += NBLK * NTHR) {
        int s = esrc[e], d = edst[e], r = erel[e];
        float nm = enorm[e];
        const float4* hp = reinterpret_cast<const float4*>(h1 + (size_t)s * HD);
        float4 hv0 = hp[0], hv1 = hp[1], hv2 = hp[2], hv3 = hp[3];
        float hs[16] = {fmaxf(hv0.x, 0.f), fmaxf(hv0.y, 0.f), fmaxf(hv0.z, 0.f), fmaxf(hv0.w, 0.f),
                        fmaxf(hv1.x, 0.f), fmaxf(hv1.y, 0.f), fmaxf(hv1.z, 0.f), fmaxf(hv1.w, 0.f),
                        fmaxf(hv2.x, 0.f), fmaxf(hv2.y, 0.f), fmaxf(hv2.z, 0.f), fmaxf(hv2.w, 0.f),
                        fmaxf(hv3.x, 0.f), fmaxf(hv3.y, 0.f), fmaxf(hv3.z, 0.f), fmaxf(hv3.w, 0.f)};
        float acc[8];
        #pragma unroll
        for (int h = 0; h < 8; ++h) acc[h] = 0.f;
        const float* wr = w + r * 132;
        #pragma unroll
        for (int i = 0; i < 16; ++i) {
            float hi = hs[i];
            const float4* wp = reinterpret_cast<const float4*>(wr + i * 8);
            fma4(acc + 0, hi, wp[0]);
            fma4(acc + 4, hi, wp[1]);
        }
        float* outp = h2 + (size_t)d * OD;
        #pragma unroll
        for (int h = 0; h < 8; ++h) atomicAdd(outp + h, nm * acc[h]);
    }
}

__global__ __launch_bounds__(NTHR) void k_softmax(const float* __restrict__ h2, float* __restrict__ out) {
    int n = blockIdx.x * NTHR + threadIdx.x;
    if (n >= N_NODES) return;
    const float4* p = reinterpret_cast<const float4*>(h2 + (size_t)n * OD);
    float4 a = p[0], b = p[1];
    float v[8] = {a.x, a.y, a.z, a.w, b.x, b.y, b.z, b.w};
    float m = v[0];
    #pragma unroll
    for (int i = 1; i < 8; ++i) m = fmaxf(m, v[i]);
    float ssum = 0.f;
    #pragma unroll
    for (int i = 0; i < 8; ++i) {
        v[i] = __expf(v[i] - m);
        ssum += v[i];
    }
    float inv = 1.0f / ssum;
    float4* q = reinterpret_cast<float4*>(out + (size_t)n * OD);
    q[0] = make_float4(v[0] * inv, v[1] * inv, v[2] * inv, v[3] * inv);
    q[1] = make_float4(v[4] * inv, v[5] * inv, v[6] * inv, v[7] * inv);
}

// =========================================================================

extern "C" void kernel_launch(void* const* d_in, const int* in_sizes, int n_in,
                              void* d_out, int out_size, void* d_ws, size_t ws_size,
                              hipStream_t stream) {
    const int* esrc = (const int*)d_in[0];
    const int* edst = (const int*)d_in[1];
    const int* erel = (const int*)d_in[2];
    const float* enorm = (const float*)d_in[3];
    const float* W0 = (const float*)d_in[4];
    const float* C0 = (const float*)d_in[5];
    const float* W1 = (const float*)d_in[6];
    const float* C1 = (const float*)d_in[7];
    const float* W2 = (const float*)d_in[8];
    const float* C2 = (const float*)d_in[9];
    const int nsb = (N_NODES + NTHR - 1) / NTHR;  // 391

    if (ws_size >= (size_t)201000000) {
        char* wsb = (char*)d_ws;
        u32* emb = (u32*)wsb;                             // fp8 tables: 80 MB (emb0/emb1), 40 MB (emb2)
        uint2* tmp = (uint2*)(wsb + 80000000);            // 25.6 MB (after emb0 region; e0f-tail
                                                          //  writes emb[0,80MB) concurrently)
        uint2* rec = (uint2*)(wsb + 160000000);           // 25,600,000
        u32* h0b = (u32*)(wsb + 185600000);               //  3,200,000 (bf16x16 rows)
        u32* h1b = (u32*)(wsb + 188800000);               //  3,200,000
        ushort* wf1 = (ushort*)(wsb + 192000000);         //     25,600 B
        ushort* wf2 = (ushort*)(wsb + 192051200);         //     13,312 B
        int* row_ptr = (int*)(wsb + 192102400);           //    400,004
        int* cntK = (int*)(wsb + 192502404);              //    802,816
        int* runstartK = (int*)(wsb + 193305220);         //    802,816
        int* total = (int*)(wsb + 194108036);             //        784

        k_p1<<<P1B + WFB + E0B, NTHR, 0, stream>>>(esrc, edst, erel, enorm, tmp, cntK, runstartK,
                                                   W1, C1, W2, C2, wf1, wf2, W0, C0, emb);
        k_tot<<<NBKT, NTHR, 0, stream>>>(cntK, total);
        k_p2<<<NBKT, 1024, 0, stream>>>(tmp, cntK, runstartK, total, rec, row_ptr);

        k_g16b<<<6250, NTHR, 0, stream>>>(rec, row_ptr, emb, h0b, 200, 4);       // [n][r] layout
        k_e1f<<<1563, NTHR, 0, stream>>>((const uint4*)wf1, (const uint4*)h0b, emb);
        k_g16b<<<6250, NTHR, 0, stream>>>(rec, row_ptr, emb, h1b, 4, 400000);    // [r][n] layout
        k_e2f<<<813, NTHR, 0, stream>>>((const uint4*)wf2, (const uint4*)h1b, emb);
        k_g8sm<<<6250, NTHR, 0, stream>>>(rec, row_ptr, emb, (float*)d_out);
    } else {
        // ---- Tier B: atomics fallback ----
        float* ws = (float*)d_ws;
        float* h0 = ws;
        float* h1 = ws + 1600000;
        float* h2 = ws + 3200000;
        float* Wr1 = ws + 4000000;
        float* Wr2 = ws + 4012800;

        (void)hipMemsetAsync(h0, 0, (size_t)4000000 * sizeof(float), stream);
        k_wr<<<75, NTHR, 0, stream>>>(W1, C1, W2, C2, Wr1, Wr2);
        k_l0_old<<<NBLK, NTHR, 0, stream>>>(esrc, edst, erel, enorm, W0, C0, h0);
        k_l1_old<<<NBLK, NTHR, 0, stream>>>(esrc, edst, erel, enorm, h0, Wr1, h1);
        k_l2_old<<<NBLK, NTHR, 0, stream>>>(esrc, edst, erel, enorm, h1, Wr2, h2);
        k_softmax<<<nsb, NTHR, 0, stream>>>(h2, (float*)d_out);
    }
}

// Round 18
// 350.131 us; speedup vs baseline: 1.0219x; 1.0219x over previous
//
#include <hip/hip_runtime.h>
#include <cstddef>
#include <cstdint>

#define E_TOTAL 3200000
#define N_NODES 100000
#define N_RELS 50
#define N_BASES 16
#define HD 16
#define OD 8
#define NTHR 256

#define NBKT 196       // coarse buckets: dst >> 9 (512 dsts each)
#define P1B 1024       // p1 blocks
#define P1C 3125       // edges per p1 block
#define WFB 76         // wrf tail blocks
#define E0B 1563       // e0f tail blocks
#define FP8_SCALE 256.0f
#define FP8_INV (1.0f / 256.0f)

typedef unsigned int u32;
typedef __attribute__((ext_vector_type(8))) short s16x8;
typedef __attribute__((ext_vector_type(4))) float f32x4;
typedef __attribute__((ext_vector_type(16))) float f32x16;

__device__ __forceinline__ u32 cvtpk(float x0, float x1) {  // v_cvt_pk_bf16_f32 (RNE)
    u32 r;
    asm("v_cvt_pk_bf16_f32 %0, %1, %2" : "=v"(r) : "v"(x0), "v"(x1));
    return r;
}
__device__ __forceinline__ ushort bf16r(float x) {
    u32 a = __float_as_uint(x);
    return (ushort)((a + 0x7fffu + ((a >> 16) & 1u)) >> 16);
}
__device__ __forceinline__ s16x8 as_s16x8(uint4 u) {
    union { uint4 u; s16x8 s; } x; x.u = u; return x.s;
}

// ---- fp8: HW pack/unpack (self-consistent encoding on gfx950) ----
#if __has_builtin(__builtin_amdgcn_cvt_pk_fp8_f32)
__device__ __forceinline__ u32 pk8x4(float a, float b, float c, float d) {
    int v = __builtin_amdgcn_cvt_pk_fp8_f32(a, b, 0, false);   // low word
    v = __builtin_amdgcn_cvt_pk_fp8_f32(c, d, v, true);        // high word
    return (u32)v;
}
#else
__device__ __forceinline__ u32 pk8(float v) {
    u32 x = __float_as_uint(v);
    u32 s = (x >> 24) & 0x80u;
    u32 ax = x & 0x7fffffffu;
    int e = (int)(ax >> 23) - 127;
    if (e < -9) return s;
    if (e < -6) {
        u32 m = (u32)rintf(__uint_as_float(ax) * 512.0f);
        if (m == 0) return s;
        if (m >= 8) return s | 0x08u;
        return s | m;
    }
    u32 m = ax & 0x7fffffu;
    u32 keep = m >> 20, rest = m & 0xFFFFFu;
    keep += (rest > 0x80000u) || (rest == 0x80000u && (keep & 1u));
    u32 ee = (u32)(e + 7);
    if (keep == 8u) { keep = 0u; ee += 1u; }
    if (ee > 15u || (ee == 15u && keep == 7u)) return s | 0x7eu;
    return s | (ee << 3) | keep;
}
__device__ __forceinline__ u32 pk8x4(float a, float b, float c, float d) {
    return pk8(a) | (pk8(b) << 8) | (pk8(c) << 16) | (pk8(d) << 24);
}
#endif
#if __has_builtin(__builtin_amdgcn_cvt_f32_fp8)
template <int SEL>
__device__ __forceinline__ float up8(u32 q) { return __builtin_amdgcn_cvt_f32_fp8(q, SEL); }
#else
template <int SEL>
__device__ __forceinline__ float up8(u32 q) {
    u32 b = (q >> (SEL * 8)) & 0xffu;
    u32 em = b & 0x7fu;
    float v = (em >= 8u) ? __uint_as_float((((em >> 3) + 120u) << 23) | ((em & 7u) << 20))
                         : (float)em * (1.0f / 512.0f);
    return (b & 0x80u) ? -v : v;
}
#endif

// ====== p1 (fused with wrf-frag build AND e0f table build — all independent) ======
// wf1: 25 rel-pairs (32x32x16 A-frags); wf2: 13 groups of 4 rels.
// e0f segment: emb0[n][r][h] fp8 via MFMA (A = W0 slot-tile, B = 256*C0).
__global__ __launch_bounds__(NTHR) void k_p1(const int* __restrict__ esrc, const int* __restrict__ edst,
                                             const int* __restrict__ erel, const float* __restrict__ enorm,
                                             uint2* __restrict__ tmp, int* __restrict__ cntK,
                                             int* __restrict__ runstartK,
                                             const float* __restrict__ W1, const float* __restrict__ C1,
                                             const float* __restrict__ W2, const float* __restrict__ C2,
                                             ushort* __restrict__ f1, ushort* __restrict__ f2,
                                             const float* __restrict__ W0, const float* __restrict__ C0,
                                             u32* __restrict__ emb) {
    __shared__ int lcnt[NBKT];
    __shared__ int sc[NTHR];
    __shared__ int lcur[NBKT];
    __shared__ uint2 stage[P1C];  // 25 KB
    int tid = threadIdx.x;
    if (blockIdx.x >= P1B + WFB) {  // ---- e0f tail blocks ----
        const f32x16 z16 = {0.f, 0.f, 0.f, 0.f, 0.f, 0.f, 0.f, 0.f,
                            0.f, 0.f, 0.f, 0.f, 0.f, 0.f, 0.f, 0.f};
        int lane = tid & 63;
        int col = lane & 31, hi = lane >> 5;
        s16x8 bf0, bf1;
        {
            float v[8];
            #pragma unroll
            for (int e = 0; e < 8; ++e) v[e] = C0[col * 16 + hi * 8 + e] * FP8_SCALE;
            bf0 = as_s16x8(make_uint4(cvtpk(v[0], v[1]), cvtpk(v[2], v[3]),
                                      cvtpk(v[4], v[5]), cvtpk(v[6], v[7])));
            int r1 = col + 32;
            #pragma unroll
            for (int e = 0; e < 8; ++e) v[e] = (r1 < N_RELS) ? C0[r1 * 16 + hi * 8 + e] * FP8_SCALE : 0.f;
            bf1 = as_s16x8(make_uint4(cvtpk(v[0], v[1]), cvtpk(v[2], v[3]),
                                      cvtpk(v[4], v[5]), cvtpk(v[6], v[7])));
        }
        int w = ((blockIdx.x - P1B - WFB) * NTHR + tid) >> 6;
        int nw = (E0B * NTHR) >> 6;
        bool g1ok = (col + 32) < N_RELS;
        for (int t = w; t < 50000; t += nw) {
            size_t gs = (size_t)t * 32 + col;
            float a[8];
            #pragma unroll
            for (int e = 0; e < 8; ++e)
                a[e] = W0[(size_t)(hi * 8 + e) * (N_NODES * HD) + gs];
            s16x8 af = as_s16x8(make_uint4(cvtpk(a[0], a[1]), cvtpk(a[2], a[3]),
                                           cvtpk(a[4], a[5]), cvtpk(a[6], a[7])));
            f32x16 d0 = __builtin_amdgcn_mfma_f32_32x32x16_bf16(af, bf0, z16, 0, 0, 0);
            f32x16 d1 = __builtin_amdgcn_mfma_f32_32x32x16_bf16(af, bf1, z16, 0, 0, 0);
            #pragma unroll
            for (int j = 0; j < 4; ++j) {
                size_t base = ((size_t)(t * 2 + (j >> 1)) * 50) * 4 + (size_t)((j & 1) * 2 + hi);
                emb[base + (size_t)col * 4] = pk8x4(d0[4 * j], d0[4 * j + 1], d0[4 * j + 2], d0[4 * j + 3]);
                if (g1ok)
                    emb[base + (size_t)(col + 32) * 4] =
                        pk8x4(d1[4 * j], d1[4 * j + 1], d1[4 * j + 2], d1[4 * j + 3]);
            }
        }
        return;
    }
    if (blockIdx.x >= P1B) {  // ---- wrf tail blocks ----
        int idx = (blockIdx.x - P1B) * NTHR + tid;
        if (idx < 25 * 512) {  // wf1
            int p = idx >> 9, rem = idx & 511, lane = rem >> 3, e = rem & 7;
            int m = lane & 31, kk = ((lane >> 5) << 3) + e;
            int r = 2 * p + (m >> 4), o = m & 15;
            float acc = 0.f;
            #pragma unroll
            for (int b = 0; b < N_BASES; ++b)
                acc = fmaf(C1[r * N_BASES + b], W1[b * 256 + kk * 16 + o], acc);
            f1[idx] = bf16r(acc * FP8_SCALE);
        } else if (idx < 25 * 512 + 13 * 512) {  // wf2
            int j = idx - 25 * 512;
            int g = j >> 9, rem = j & 511, lane = rem >> 3, e = rem & 7;
            int m = lane & 31, kk = ((lane >> 5) << 3) + e;
            int rl = 4 * g + (m >> 3), o = m & 7;
            float acc = 0.f;
            if (rl < N_RELS) {
                #pragma unroll
                for (int b = 0; b < N_BASES; ++b)
                    acc = fmaf(C2[rl * N_BASES + b], W2[b * 128 + kk * 8 + o], acc);
            }
            f2[j] = bf16r(acc * FP8_SCALE);
        }
        return;
    }
    for (int i = tid; i < NBKT; i += NTHR) lcnt[i] = 0;
    __syncthreads();
    int e0 = blockIdx.x * P1C;
    u32 rx[13], rn[13];
    int rb[13];
    #pragma unroll
    for (int j = 0; j < 13; ++j) {
        int i = tid + j * NTHR;
        rb[j] = -1;
        if (i < P1C) {
            int e = e0 + i;
            int d = edst[e];
            int b = d >> 9;
            rb[j] = b;
            rx[j] = (u32)esrc[e] | ((u32)erel[e] << 17) | ((u32)(d & 511) << 23);
            rn[j] = __float_as_uint(enorm[e]);
            atomicAdd(&lcnt[b], 1);
        }
    }
    __syncthreads();
    int own = (tid < NBKT) ? lcnt[tid] : 0;
    sc[tid] = own;
    __syncthreads();
    #pragma unroll
    for (int off = 1; off < NTHR; off <<= 1) {
        int t = (tid >= off) ? sc[tid - off] : 0;
        __syncthreads();
        sc[tid] += t;
        __syncthreads();
    }
    if (tid < NBKT) lcur[tid] = sc[tid] - own;
    __syncthreads();
    #pragma unroll
    for (int j = 0; j < 13; ++j) {
        if (rb[j] >= 0) {
            int pos = atomicAdd(&lcur[rb[j]], 1);
            stage[pos] = make_uint2(rx[j], rn[j]);
        }
    }
    __syncthreads();
    for (int i = tid; i < P1C; i += NTHR)
        tmp[(size_t)blockIdx.x * P1C + i] = stage[i];
    for (int b = tid; b < NBKT; b += NTHR) {
        int excl = lcur[b] - lcnt[b];
        cntK[blockIdx.x * NBKT + b] = lcnt[b];
        runstartK[blockIdx.x * NBKT + b] = blockIdx.x * P1C + excl;
    }
}

// bucket totals
__global__ __launch_bounds__(NTHR) void k_tot(const int* __restrict__ cntK, int* __restrict__ total) {
    int b = blockIdx.x;
    __shared__ int s[NTHR];
    int tid = threadIdx.x;
    int acc = 0;
    for (int k = tid; k < P1B; k += NTHR) acc += cntK[k * NBKT + b];
    s[tid] = acc;
    __syncthreads();
    for (int off = NTHR / 2; off > 0; off >>= 1) {
        if (tid < off) s[tid] += s[tid + off];
        __syncthreads();
    }
    if (tid == 0) total[b] = s[0];
}

// p2: self-computed base + per-dst sort within bucket (L2-resident window)
__global__ __launch_bounds__(1024) void k_p2(const uint2* __restrict__ tmp, const int* __restrict__ cntK,
                                             const int* __restrict__ runstartK, const int* __restrict__ total,
                                             uint2* __restrict__ rec, int* __restrict__ row_ptr) {
    int b = blockIdx.x;
    int tid = threadIdx.x;
    __shared__ int dcnt[512], dscan[512];
    __shared__ int gbs;
    if (tid < 256) dcnt[tid] = (tid < b && tid < NBKT) ? total[tid] : 0;
    __syncthreads();
    for (int off = 128; off > 0; off >>= 1) {
        if (tid < off) dcnt[tid] += dcnt[tid + off];
        __syncthreads();
    }
    if (tid == 0) gbs = dcnt[0];
    __syncthreads();
    int gbase = gbs;
    if (tid < 512) dcnt[tid] = 0;
    __syncthreads();
    int mycnt = cntK[tid * NBKT + b];
    int myrs = runstartK[tid * NBKT + b];
    for (int i = 0; i < mycnt; ++i)
        atomicAdd(&dcnt[tmp[myrs + i].x >> 23], 1);
    __syncthreads();
    if (tid < 512) dscan[tid] = dcnt[tid];
    __syncthreads();
    for (int off = 1; off < 512; off <<= 1) {
        int v = (tid >= off && tid < 512) ? dscan[tid - off] : 0;
        __syncthreads();
        if (tid < 512) dscan[tid] += v;
        __syncthreads();
    }
    if (tid < 512) {
        int excl = gbase + dscan[tid] - dcnt[tid];
        int d = (b << 9) + tid;
        if (d < N_NODES) row_ptr[d] = excl;
        dscan[tid] = excl;
    }
    if (b == NBKT - 1 && tid == 0) row_ptr[N_NODES] = E_TOTAL;
    __syncthreads();
    for (int i = 0; i < mycnt; ++i) {
        uint2 t = tmp[myrs + i];
        int pos = atomicAdd(&dscan[t.x >> 23], 1);
        rec[pos] = make_uint2(t.x & 0x7FFFFFu, t.y);
    }
}

// gather 16-dim fp8 rows by (rel,src), parametric layout, relu-fused, bf16x16 row out.
// 16 edge-groups x 4 lanes; 2-edge unroll for memory-level parallelism.
__global__ __launch_bounds__(NTHR) void k_g16b(const uint2* __restrict__ rec, const int* __restrict__ row_ptr,
                                               const u32* __restrict__ tbl, u32* __restrict__ hb,
                                               int srcMul, int relMul) {
    int lane = threadIdx.x & 63;
    int g = lane >> 2, l = lane & 3;
    int wave = (blockIdx.x * NTHR + threadIdx.x) >> 6;
    int nw = (gridDim.x * NTHR) >> 6;
    for (int d = wave; d < N_NODES; d += nw) {
        int s0 = row_ptr[d], s1 = row_ptr[d + 1];
        float a0 = 0.f, a1 = 0.f, a2 = 0.f, a3 = 0.f;
        for (int j = s0 + g; j < s1; j += 32) {
            uint2 rc0 = rec[j];
            int j1 = j + 16;
            bool ok = j1 < s1;
            uint2 rc1 = ok ? rec[j1] : make_uint2(0u, 0u);
            int src0 = rc0.x & 0x1FFFF, rel0 = rc0.x >> 17;
            float nm0 = __uint_as_float(rc0.y) * FP8_INV;
            int src1 = rc1.x & 0x1FFFF, rel1 = rc1.x >> 17;
            float nm1 = ok ? __uint_as_float(rc1.y) * FP8_INV : 0.f;
            u32 q0 = tbl[(size_t)src0 * srcMul + (size_t)rel0 * relMul + l];
            u32 q1 = tbl[(size_t)src1 * srcMul + (size_t)rel1 * relMul + l];
            a0 = fmaf(nm0, up8<0>(q0), a0);
            a1 = fmaf(nm0, up8<1>(q0), a1);
            a2 = fmaf(nm0, up8<2>(q0), a2);
            a3 = fmaf(nm0, up8<3>(q0), a3);
            a0 = fmaf(nm1, up8<0>(q1), a0);
            a1 = fmaf(nm1, up8<1>(q1), a1);
            a2 = fmaf(nm1, up8<2>(q1), a2);
            a3 = fmaf(nm1, up8<3>(q1), a3);
        }
        a0 += __shfl_xor(a0, 4);  a1 += __shfl_xor(a1, 4);  a2 += __shfl_xor(a2, 4);  a3 += __shfl_xor(a3, 4);
        a0 += __shfl_xor(a0, 8);  a1 += __shfl_xor(a1, 8);  a2 += __shfl_xor(a2, 8);  a3 += __shfl_xor(a3, 8);
        a0 += __shfl_xor(a0, 16); a1 += __shfl_xor(a1, 16); a2 += __shfl_xor(a2, 16); a3 += __shfl_xor(a3, 16);
        a0 += __shfl_xor(a0, 32); a1 += __shfl_xor(a1, 32); a2 += __shfl_xor(a2, 32); a3 += __shfl_xor(a3, 32);
        if (lane < 4) {
            uint2 pk = make_uint2(cvtpk(fmaxf(a0, 0.f), fmaxf(a1, 0.f)),
                                  cvtpk(fmaxf(a2, 0.f), fmaxf(a3, 0.f)));
            *(uint2*)(hb + (size_t)d * 8 + l * 2) = pk;  // fused relu, bf16
        }
    }
}

// emb1 via 32x32x16 MFMA: M=32 = 2 rels x 16 o, N=32 nodes, K=16 (exact). [r][n] layout.
__global__ __launch_bounds__(NTHR) void k_e1f(const uint4* __restrict__ wfrag, const uint4* __restrict__ hb,
                                              u32* __restrict__ emb) {
    const f32x16 z16 = {0.f, 0.f, 0.f, 0.f, 0.f, 0.f, 0.f, 0.f,
                        0.f, 0.f, 0.f, 0.f, 0.f, 0.f, 0.f, 0.f};
    int lane = threadIdx.x & 63;
    int w = (blockIdx.x * NTHR + threadIdx.x) >> 6;
    int p = w / 250, c = w % 250;  // 25 pairs x 250 slots
    if (p >= 25) return;
    s16x8 af = as_s16x8(wfrag[p * 64 + lane]);
    int col = lane & 31, hi = lane >> 5;
    size_t r0b = (size_t)(2 * p) * 400000, r1b = (size_t)(2 * p + 1) * 400000;
    for (int t = c; t < 3125; t += 250) {
        uint4 hq = hb[(size_t)(t * 32 + col) * 2 + hi];  // 1 KB/wave: 32 node rows
        f32x16 d = __builtin_amdgcn_mfma_f32_32x32x16_bf16(af, as_s16x8(hq), z16, 0, 0, 0);
        u32 A0 = pk8x4(d[0], d[1], d[2], d[3]);
        u32 B0 = pk8x4(d[4], d[5], d[6], d[7]);
        u32 A1 = pk8x4(d[8], d[9], d[10], d[11]);
        u32 B1 = pk8x4(d[12], d[13], d[14], d[15]);
        u32 pA0 = (u32)__shfl_xor((int)A0, 32);
        u32 pB0 = (u32)__shfl_xor((int)B0, 32);
        u32 pA1 = (u32)__shfl_xor((int)A1, 32);
        u32 pB1 = (u32)__shfl_xor((int)B1, 32);
        u32 off = t * 128 + col * 4;
        if (hi == 0) {
            *(uint2*)(emb + r0b + off) = make_uint2(A0, pA0);
            *(uint2*)(emb + r1b + off) = make_uint2(A1, pA1);
        } else {
            *(uint2*)(emb + r0b + off + 2) = make_uint2(pB0, B0);
            *(uint2*)(emb + r1b + off + 2) = make_uint2(pB1, B1);
        }
    }
}

// emb2 via 32x32x16 MFMA: M=32 = 4 rels x 8 o. [r][n] layout, no shuffles.
__global__ __launch_bounds__(NTHR) void k_e2f(const uint4* __restrict__ wfrag, const uint4* __restrict__ hb,
                                              u32* __restrict__ emb) {
    const f32x16 z16 = {0.f, 0.f, 0.f, 0.f, 0.f, 0.f, 0.f, 0.f,
                        0.f, 0.f, 0.f, 0.f, 0.f, 0.f, 0.f, 0.f};
    int lane = threadIdx.x & 63;
    int w = (blockIdx.x * NTHR + threadIdx.x) >> 6;
    int g = w / 250, c = w % 250;  // 13 groups x 250 slots
    if (g >= 13) return;
    s16x8 af = as_s16x8(wfrag[g * 64 + lane]);
    int col = lane & 31, hi = lane >> 5;
    for (int t = c; t < 3125; t += 250) {
        uint4 hq = hb[(size_t)(t * 32 + col) * 2 + hi];
        f32x16 d = __builtin_amdgcn_mfma_f32_32x32x16_bf16(af, as_s16x8(hq), z16, 0, 0, 0);
        #pragma unroll
        for (int j = 0; j < 4; ++j) {
            int rl = 4 * g + j;
            if (rl >= N_RELS) break;  // wave-uniform
            u32 wj = pk8x4(d[4 * j], d[4 * j + 1], d[4 * j + 2], d[4 * j + 3]);
            emb[(size_t)rl * 200000 + t * 64 + col * 2 + hi] = wj;
        }
    }
}

// gather 8-dim fp8 rows + fused softmax. 32 edge-groups x 2 lanes.
__global__ __launch_bounds__(NTHR) void k_g8sm(const uint2* __restrict__ rec, const int* __restrict__ row_ptr,
                                               const u32* __restrict__ tbl, float* __restrict__ out) {
    int lane = threadIdx.x & 63;
    int g = lane >> 1, l = lane & 1;
    int wave = (blockIdx.x * NTHR + threadIdx.x) >> 6;
    int nw = (gridDim.x * NTHR) >> 6;
    for (int d = wave; d < N_NODES; d += nw) {
        int s0 = row_ptr[d], s1 = row_ptr[d + 1];
        float a0 = 0.f, a1 = 0.f, a2 = 0.f, a3 = 0.f;
        for (int j = s0 + g; j < s1; j += 32) {
            uint2 rc = rec[j];
            int src = rc.x & 0x1FFFF;
            int rel = rc.x >> 17;
            float nm = __uint_as_float(rc.y) * FP8_INV;
            u32 q = tbl[((size_t)rel * N_NODES + src) * 2 + l];
            a0 = fmaf(nm, up8<0>(q), a0);
            a1 = fmaf(nm, up8<1>(q), a1);
            a2 = fmaf(nm, up8<2>(q), a2);
            a3 = fmaf(nm, up8<3>(q), a3);
        }
        a0 += __shfl_xor(a0, 2);  a1 += __shfl_xor(a1, 2);  a2 += __shfl_xor(a2, 2);  a3 += __shfl_xor(a3, 2);
        a0 += __shfl_xor(a0, 4);  a1 += __shfl_xor(a1, 4);  a2 += __shfl_xor(a2, 4);  a3 += __shfl_xor(a3, 4);
        a0 += __shfl_xor(a0, 8);  a1 += __shfl_xor(a1, 8);  a2 += __shfl_xor(a2, 8);  a3 += __shfl_xor(a3, 8);
        a0 += __shfl_xor(a0, 16); a1 += __shfl_xor(a1, 16); a2 += __shfl_xor(a2, 16); a3 += __shfl_xor(a3, 16);
        a0 += __shfl_xor(a0, 32); a1 += __shfl_xor(a1, 32); a2 += __shfl_xor(a2, 32); a3 += __shfl_xor(a3, 32);
        float mx = fmaxf(fmaxf(a0, a1), fmaxf(a2, a3));
        mx = fmaxf(mx, __shfl_xor(mx, 1));
        float e0 = __expf(a0 - mx), e1 = __expf(a1 - mx), e2 = __expf(a2 - mx), e3 = __expf(a3 - mx);
        float sm = e0 + e1 + e2 + e3;
        sm += __shfl_xor(sm, 1);
        float inv = 1.0f / sm;
        if (lane < 2)
            *(float4*)(out + (size_t)d * OD + l * 4) = make_float4(e0 * inv, e1 * inv, e2 * inv, e3 * inv);
    }
}

// ======= TIER B fallback (atomics, 16.1 MB) =======
#define NBLK 2560

__device__ __forceinline__ void fma4(float* acc, float c, float4 w) {
    acc[0] = fmaf(c, w.x, acc[0]);
    acc[1] = fmaf(c, w.y, acc[1]);
    acc[2] = fmaf(c, w.z, acc[2]);
    acc[3] = fmaf(c, w.w, acc[3]);
}

__global__ __launch_bounds__(NTHR) void k_wr(const float* __restrict__ W1, const float* __restrict__ C1,
                                             const float* __restrict__ W2, const float* __restrict__ C2,
                                             float* __restrict__ Wr1, float* __restrict__ Wr2) {
    int idx = blockIdx.x * NTHR + threadIdx.x;
    const int n1 = N_RELS * 256;
    if (idx < n1) {
        int r = idx >> 8, io = idx & 255;
        float acc = 0.f;
        #pragma unroll
        for (int b = 0; b < N_BASES; ++b)
            acc = fmaf(C1[r * N_BASES + b], W1[b * 256 + io], acc);
        Wr1[idx] = acc;
    } else if (idx < n1 + N_RELS * 128) {
        int j = idx - n1;
        int r = j >> 7, io = j & 127;
        float acc = 0.f;
        #pragma unroll
        for (int b = 0; b < N_BASES; ++b)
            acc = fmaf(C2[r * N_BASES + b], W2[b * 128 + io], acc);
        Wr2[j] = acc;
    }
}

__global__ __launch_bounds__(NTHR) void k_l0_old(const int* __restrict__ esrc, const int* __restrict__ edst,
                                                 const int* __restrict__ erel, const float* __restrict__ enorm,
                                                 const float* __restrict__ W0, const float* __restrict__ C0,
                                                 float* __restrict__ h0) {
    for (int e = blockIdx.x * NTHR + threadIdx.x; e < E_TOTAL; e += NBLK * NTHR) {
        int s = esrc[e], d = edst[e], r = erel[e];
        float nm = enorm[e];
        const float4* cp = reinterpret_cast<const float4*>(C0 + r * N_BASES);
        float4 c0 = cp[0], c1 = cp[1], c2 = cp[2], c3 = cp[3];
        float coef[16] = {c0.x, c0.y, c0.z, c0.w, c1.x, c1.y, c1.z, c1.w,
                          c2.x, c2.y, c2.z, c2.w, c3.x, c3.y, c3.z, c3.w};
        float acc[16];
        #pragma unroll
        for (int h = 0; h < 16; ++h) acc[h] = 0.f;
        const float* wbase = W0 + (size_t)s * HD;
        #pragma unroll
        for (int b = 0; b < N_BASES; ++b) {
            const float4* wp = reinterpret_cast<const float4*>(wbase + (size_t)b * (N_NODES * HD));
            float cb = coef[b];
            fma4(acc + 0, cb, wp[0]);
            fma4(acc + 4, cb, wp[1]);
            fma4(acc + 8, cb, wp[2]);
            fma4(acc + 12, cb, wp[3]);
        }
        float* outp = h0 + (size_t)d * HD;
        #pragma unroll
        for (int h = 0; h < 16; ++h) atomicAdd(outp + h, nm * acc[h]);
    }
}

__global__ __launch_bounds__(NTHR) void k_l1_old(const int* __restrict__ esrc, const int* __restrict__ edst,
                                                 const int* __restrict__ erel, const float* __restrict__ enorm,
                                                 const float* __restrict__ h0, const float* __restrict__ Wr1,
                                                 float* __restrict__ h1) {
    __shared__ float w[N_RELS * 260];
    for (int i = threadIdx.x; i < N_RELS * 256; i += NTHR) {
        int r = i >> 8, rest = i & 255;
        w[r * 260 + rest] = Wr1[i];
    }
    __syncthreads();
    for (int e = blockIdx.x * NTHR + threadIdx.x; e < E_TOTAL; e += NBLK * NTHR) {
        int s = esrc[e], d = edst[e], r = erel[e];
        float nm = enorm[e];
        const float4* hp = reinterpret_cast<const float4*>(h0 + (size_t)s * HD);
        float4 hv0 = hp[0], hv1 = hp[1], hv2 = hp[2], hv3 = hp[3];
        float hs[16] = {fmaxf(hv0.x, 0.f), fmaxf(hv0.y, 0.f), fmaxf(hv0.z, 0.f), fmaxf(hv0.w, 0.f),
                        fmaxf(hv1.x, 0.f), fmaxf(hv1.y, 0.f), fmaxf(hv1.z, 0.f), fmaxf(hv1.w, 0.f),
                        fmaxf(hv2.x, 0.f), fmaxf(hv2.y, 0.f), fmaxf(hv2.z, 0.f), fmaxf(hv2.w, 0.f),
                        fmaxf(hv3.x, 0.f), fmaxf(hv3.y, 0.f), fmaxf(hv3.z, 0.f), fmaxf(hv3.w, 0.f)};
        float acc[16];
        #pragma unroll
        for (int h = 0; h < 16; ++h) acc[h] = 0.f;
        const float* wr = w + r * 260;
        #pragma unroll
        for (int i = 0; i < 16; ++i) {
            float hi = hs[i];
            const float4* wp = reinterpret_cast<const float4*>(wr + i * 16);
            fma4(acc + 0, hi, wp[0]);
            fma4(acc + 4, hi, wp[1]);
            fma4(acc + 8, hi, wp[2]);
            fma4(acc + 12, hi, wp[3]);
        }
        float* outp = h1 + (size_t)d * HD;
        #pragma unroll
        for (int h = 0; h < 16; ++h) atomicAdd(outp + h, nm * acc[h]);
    }
}

__global__ __launch_bounds__(NTHR) void k_l2_old(const int* __restrict__ esrc, const int* __restrict__ edst,
                                                 const int* __restrict__ erel, const float* __restrict__ enorm,
                                                 const float* __restrict__ h1, const float* __restrict__ Wr2,
                                                 float* __restrict__ h2) {
    __shared__ float w[N_RELS * 132];
    for (int i = threadIdx.x; i < N_RELS * 128; i += NTHR) {
        int r = i >> 7, rest = i & 127;
        w[r * 132 + rest] = Wr2[i];
    }
    __syncthreads();
    for (int e = blockIdx.x * NTHR + threadIdx.x; e < E_TOTAL; e += NBLK * NTHR) {
        int s = esrc[e], d = edst[e], r = erel[e];
        float nm = enorm[e];
        const float4* hp = reinterpret_cast<const float4*>(h1 + (size_t)s * HD);
        float4 hv0 = hp[0], hv1 = hp[1], hv2 = hp[2], hv3 = hp[3];
        float hs[16] = {fmaxf(hv0.x, 0.f), fmaxf(hv0.y, 0.f), fmaxf(hv0.z, 0.f), fmaxf(hv0.w, 0.f),
                        fmaxf(hv1.x, 0.f), fmaxf(hv1.y, 0.f), fmaxf(hv1.z, 0.f), fmaxf(hv1.w, 0.f),
                        fmaxf(hv2.x, 0.f), fmaxf(hv2.y, 0.f), fmaxf(hv2.z, 0.f), fmaxf(hv2.w, 0.f),
                        fmaxf(hv3.x, 0.f), fmaxf(hv3.y, 0.f), fmaxf(hv3.z, 0.f), fmaxf(hv3.w, 0.f)};
        float acc[8];
        #pragma unroll
        for (int h = 0; h < 8; ++h) acc[h] = 0.f;
        const float* wr = w + r * 132;
        #pragma unroll
        for (int i = 0; i < 16; ++i) {
            float hi = hs[i];
            const float4* wp = reinterpret_cast<const float4*>(wr + i * 8);
            fma4(acc + 0, hi, wp[0]);
            fma4(acc + 4, hi, wp[1]);
        }
        float* outp = h2 + (size_t)d * OD;
        #pragma unroll
        for (int h = 0; h < 8; ++h) atomicAdd(outp + h, nm * acc[h]);
    }
}

__global__ __launch_bounds__(NTHR) void k_softmax(const float* __restrict__ h2, float* __restrict__ out) {
    int n = blockIdx.x * NTHR + threadIdx.x;
    if (n >= N_NODES) return;
    const float4* p = reinterpret_cast<const float4*>(h2 + (size_t)n * OD);
    float4 a = p[0], b = p[1];
    float v[8] = {a.x, a.y, a.z, a.w, b.x, b.y, b.z, b.w};
    float m = v[0];
    #pragma unroll
    for (int i = 1; i < 8; ++i) m = fmaxf(m, v[i]);
    float ssum = 0.f;
    #pragma unroll
    for (int i = 0; i < 8; ++i) {
        v[i] = __expf(v[i] - m);
        ssum += v[i];
    }
    float inv = 1.0f / ssum;
    float4* q = reinterpret_cast<float4*>(out + (size_t)n * OD);
    q[0] = make_float4(v[0] * inv, v[1] * inv, v[2] * inv, v[3] * inv);
    q[1] = make_float4(v[4] * inv, v[5] * inv, v[6] * inv, v[7] * inv);
}

// =========================================================================

extern "C" void kernel_launch(void* const* d_in, const int* in_sizes, int n_in,
                              void* d_out, int out_size, void* d_ws, size_t ws_size,
                              hipStream_t stream) {
    const int* esrc = (const int*)d_in[0];
    const int* edst = (const int*)d_in[1];
    const int* erel = (const int*)d_in[2];
    const float* enorm = (const float*)d_in[3];
    const float* W0 = (const float*)d_in[4];
    const float* C0 = (const float*)d_in[5];
    const float* W1 = (const float*)d_in[6];
    const float* C1 = (const float*)d_in[7];
    const float* W2 = (const float*)d_in[8];
    const float* C2 = (const float*)d_in[9];
    const int nsb = (N_NODES + NTHR - 1) / NTHR;  // 391

    if (ws_size >= (size_t)201000000) {
        char* wsb = (char*)d_ws;
        u32* emb = (u32*)wsb;                             // fp8 tables: 80 MB (emb0/emb1), 40 MB (emb2)
        uint2* tmp = (uint2*)(wsb + 80000000);            // 25.6 MB (after emb0 region; e0f-tail
                                                          //  writes emb[0,80MB) concurrently)
        uint2* rec = (uint2*)(wsb + 160000000);           // 25,600,000
        u32* h0b = (u32*)(wsb + 185600000);               //  3,200,000 (bf16x16 rows)
        u32* h1b = (u32*)(wsb + 188800000);               //  3,200,000
        ushort* wf1 = (ushort*)(wsb + 192000000);         //     25,600 B
        ushort* wf2 = (ushort*)(wsb + 192051200);         //     13,312 B
        int* row_ptr = (int*)(wsb + 192102400);           //    400,004
        int* cntK = (int*)(wsb + 192502404);              //    802,816
        int* runstartK = (int*)(wsb + 193305220);         //    802,816
        int* total = (int*)(wsb + 194108036);             //        784

        k_p1<<<P1B + WFB + E0B, NTHR, 0, stream>>>(esrc, edst, erel, enorm, tmp, cntK, runstartK,
                                                   W1, C1, W2, C2, wf1, wf2, W0, C0, emb);
        k_tot<<<NBKT, NTHR, 0, stream>>>(cntK, total);
        k_p2<<<NBKT, 1024, 0, stream>>>(tmp, cntK, runstartK, total, rec, row_ptr);

        k_g16b<<<6250, NTHR, 0, stream>>>(rec, row_ptr, emb, h0b, 200, 4);       // [n][r] layout
        k_e1f<<<1563, NTHR, 0, stream>>>((const uint4*)wf1, (const uint4*)h0b, emb);
        k_g16b<<<6250, NTHR, 0, stream>>>(rec, row_ptr, emb, h1b, 4, 400000);    // [r][n] layout
        k_e2f<<<813, NTHR, 0, stream>>>((const uint4*)wf2, (const uint4*)h1b, emb);
        k_g8sm<<<6250, NTHR, 0, stream>>>(rec, row_ptr, emb, (float*)d_out);
    } else {
        // ---- Tier B: atomics fallback ----
        float* ws = (float*)d_ws;
        float* h0 = ws;
        float* h1 = ws + 1600000;
        float* h2 = ws + 3200000;
        float* Wr1 = ws + 4000000;
        float* Wr2 = ws + 4012800;

        (void)hipMemsetAsync(h0, 0, (size_t)4000000 * sizeof(float), stream);
        k_wr<<<75, NTHR, 0, stream>>>(W1, C1, W2, C2, Wr1, Wr2);
        k_l0_old<<<NBLK, NTHR, 0, stream>>>(esrc, edst, erel, enorm, W0, C0, h0);
        k_l1_old<<<NBLK, NTHR, 0, stream>>>(esrc, edst, erel, enorm, h0, Wr1, h1);
        k_l2_old<<<NBLK, NTHR, 0, stream>>>(esrc, edst, erel, enorm, h1, Wr2, h2);
        k_softmax<<<nsb, NTHR, 0, stream>>>(h2, (float*)d_out);
    }
}